// Round 1
// 669.317 us; speedup vs baseline: 1.1648x; 1.1648x over previous
//
#include <hip/hip_runtime.h>
#include <hip/hip_bf16.h>
#include <stdint.h>

// GraphConv: out = normalize((adj@x + x)@W + bias, dim=f)
// R4: k1 restructured for occupancy + hidden prefetch + swizzled LDS.
//   K0a: u[b][m][o] = x@W          (fp32 in, bf16 out, register-blocked)
//   K0b: ut[b][o][m] = u^T         (bf16 LDS transpose)
//   K1 : v = adj@u  (A: fp32->bf16 via regs + swizzled ds_write;
//                    B: global_load_lds with pre-swizzled global source)
//        epilogue: z = v + u + bias (fp32), out = z / max(||z||,eps), fp32.
// K1 geometry: 128x128 tile, 512 threads (8 waves of 32x64), BK=64,
// grid (64,8) -> 2 blocks/CU, 16 waves/CU. A-prefetch issued AFTER the
// pre-compute barrier so its latency hides under the MFMA phase.
// LDS swizzle: 16B chunk c of row r stored at chunk c^(r&7) (rows = 128B).

typedef __bf16 bf16;
typedef __bf16 bf16x8 __attribute__((ext_vector_type(8)));
typedef float floatx4 __attribute__((ext_vector_type(4)));

#define B_ 8
#define N_ 8192
#define F_ 128

__device__ __forceinline__ void async_copy16(const void* g, void* l) {
  __builtin_amdgcn_global_load_lds(
      (const __attribute__((address_space(1))) uint32_t*)g,
      (__attribute__((address_space(3))) uint32_t*)l, 16, 0, 0);
}

// ---------------- K0a: u[b][m][o] = x[b][m][:] @ W[:][o]  (fp32 -> bf16) ----
__global__ __launch_bounds__(256) void k0a_xw(const float* __restrict__ x,
                                              const float* __restrict__ w,
                                              bf16* __restrict__ u) {
  const int t = blockIdx.x * 256 + threadIdx.x;
  const int o0 = (t & 15) << 3;     // 8 consecutive outputs
  const size_t bm = (size_t)(t >> 4);
  const float* xr = x + bm * F_;
  float acc[8] = {};
  for (int f0 = 0; f0 < 128; f0 += 4) {
    float4 xv = *(const float4*)(xr + f0);
#pragma unroll
    for (int ff = 0; ff < 4; ++ff) {
      const float* wr_ = w + (size_t)(f0 + ff) * F_ + o0;
      float4 w0 = *(const float4*)(wr_);
      float4 w1 = *(const float4*)(wr_ + 4);
      float xf = (&xv.x)[ff];
      acc[0] += xf * w0.x; acc[1] += xf * w0.y;
      acc[2] += xf * w0.z; acc[3] += xf * w0.w;
      acc[4] += xf * w1.x; acc[5] += xf * w1.y;
      acc[6] += xf * w1.z; acc[7] += xf * w1.w;
    }
  }
  bf16x8 res;
#pragma unroll
  for (int jj = 0; jj < 8; ++jj) res[jj] = (bf16)acc[jj];
  *(bf16x8*)(u + bm * F_ + o0) = res;
}

// ---------------- K0b: ut[b][o][m] = u[b][m][o] (64x64 LDS transpose) ------
__global__ __launch_bounds__(256) void k0b_transpose(const bf16* __restrict__ u,
                                                     bf16* __restrict__ ut) {
  __shared__ bf16 T[64][65];
  const int b = blockIdx.z;
  const int m0 = blockIdx.x << 6;
  const int o0 = blockIdx.y << 6;
  const bf16* up = u + (size_t)b * N_ * F_;
  bf16* utp = ut + (size_t)b * F_ * N_;
#pragma unroll
  for (int c = 0; c < 16; ++c) {
    int idx = threadIdx.x + (c << 8);  // 0..4095
    int r = idx >> 6, cc = idx & 63;   // r = m-local, cc = o-local
    T[r][cc] = up[(size_t)(m0 + r) * F_ + o0 + cc];
  }
  __syncthreads();
#pragma unroll
  for (int c = 0; c < 16; ++c) {
    int idx = threadIdx.x + (c << 8);
    int r = idx >> 6, cc = idx & 63;   // r = o-local, cc = m-local
    utp[(size_t)(o0 + r) * N_ + m0 + cc] = T[cc][r];
  }
}

// ---- K1: v = adj@u; z = v + u + bias; out = z / max(||z||, eps) ----
__global__ __launch_bounds__(512, 4) void k1_graphconv(const float* __restrict__ adj,
                                                       const bf16* __restrict__ ut,
                                                       const bf16* __restrict__ unat,
                                                       const float* __restrict__ bias,
                                                       float* __restrict__ out) {
  __shared__ bf16 As[128][64];   // adj tile, bf16, chunk-swizzled
  __shared__ bf16 Bs[128][64];   // ut tile (B^T rows), chunk-swizzled
  __shared__ float ss[2][128];
  const int tid = threadIdx.x;            // 0..511
  const int lane = tid & 63;
  const int wv = tid >> 6;                // 0..7
  const int wr = wv >> 1;                 // 0..3: 32-row band
  const int wc = wv & 1;                  // 0..1: 64-col half
  const int n0 = blockIdx.x << 7;         // 64 n-tiles; XCD = n-tile % 8
  const int b = blockIdx.y;               // 8 b-blocks share adj tile in-XCD
  const bf16* ub = ut + (size_t)b * F_ * N_;

  // ---- B staging: global_load_lds, linear LDS dest, swizzled global src ----
  // phys slot for this thread = (row = tid>>3, chunk = tid&7); content must be
  // logical chunk (tid&7)^(row&7) of that row.
  const int brow = tid >> 3;                    // 0..63 (call 0), +64 (call 1)
  const int blc = (tid & 7) ^ (brow & 7);
  const bf16* gb0 = ub + (size_t)brow * N_ + (blc << 3);
  const bf16* gb1 = ub + (size_t)(brow + 64) * N_ + (blc << 3);
  bf16* lb0 = (bf16*)Bs + tid * 8;
  bf16* lb1 = (bf16*)Bs + (tid + 512) * 8;

  // ---- A staging: fp32 -> bf16 via regs, swizzled ds_write ----
  // thread: row ar = tid>>2, k-cols (tid&3)*16 .. +16  (logical chunks 2m,2m+1)
  const int ar = tid >> 2;                      // 0..127
  const int kc = (tid & 3) << 4;                // float offset in row
  const float* gAb = adj + (size_t)(n0 + ar) * N_ + kc;
  const int pc0 = ((tid & 3) << 1) ^ (ar & 7);
  bf16* lA0 = (bf16*)As + ar * 64 + (pc0 << 3);
  bf16* lA1 = (bf16*)As + ar * 64 + ((pc0 ^ 1) << 3);

  // ---- fragment read pointers (swizzle: chunk ^= row&7 == lane&7) ----
  const bf16* pa[2][2];
  const bf16* pb[4][2];
#pragma unroll
  for (int i = 0; i < 2; ++i)
#pragma unroll
    for (int kk = 0; kk < 2; ++kk)
      pa[i][kk] = &As[32 * wr + 16 * i + (lane & 15)]
                     [(((kk << 2) + (lane >> 4)) ^ (lane & 7)) << 3];
#pragma unroll
  for (int j = 0; j < 4; ++j)
#pragma unroll
    for (int kk = 0; kk < 2; ++kk)
      pb[j][kk] = &Bs[64 * wc + 16 * j + (lane & 15)]
                     [(((kk << 2) + (lane >> 4)) ^ (lane & 7)) << 3];

  floatx4 acc[2][4] = {};

  // prefetch A(ks=0)
  float4 pf[4];
#pragma unroll
  for (int q = 0; q < 4; ++q) pf[q] = *(const float4*)(gAb + 4 * q);

  for (int ks = 0; ks < 128; ++ks) {
    __syncthreads();  // compute(ks-1) readers done; pf(ks) arrived
    // B(ks) async copies — only these sit on the pre-compute drain (L2-resident)
    async_copy16(gb0, lb0);
    async_copy16(gb1, lb1);
    gb0 += 64; gb1 += 64;
    // commit A(ks) regs -> bf16 LDS (swizzled)
    bf16x8 lo, hi;
#pragma unroll
    for (int q = 0; q < 2; ++q) {
      float4 f = pf[q];
      lo[4 * q + 0] = (bf16)f.x; lo[4 * q + 1] = (bf16)f.y;
      lo[4 * q + 2] = (bf16)f.z; lo[4 * q + 3] = (bf16)f.w;
    }
#pragma unroll
    for (int q = 0; q < 2; ++q) {
      float4 f = pf[q + 2];
      hi[4 * q + 0] = (bf16)f.x; hi[4 * q + 1] = (bf16)f.y;
      hi[4 * q + 2] = (bf16)f.z; hi[4 * q + 3] = (bf16)f.w;
    }
    *(bf16x8*)lA0 = lo;
    *(bf16x8*)lA1 = hi;
    __syncthreads();  // drains B copies + A ds_writes
    // prefetch A(ks+1) AFTER the barrier: latency hides under the MFMA phase
    // (wraps to 0 on last iter to avoid OOB; value unused)
    const float* gn = gAb + ((size_t)((ks + 1) & 127) << 6);
#pragma unroll
    for (int q = 0; q < 4; ++q) pf[q] = *(const float4*)(gn + 4 * q);

#pragma unroll
    for (int kk = 0; kk < 2; ++kk) {
      bf16x8 av[2], bv[4];
#pragma unroll
      for (int i = 0; i < 2; ++i) av[i] = *(const bf16x8*)pa[i][kk];
#pragma unroll
      for (int j = 0; j < 4; ++j) bv[j] = *(const bf16x8*)pb[j][kk];
#pragma unroll
      for (int i = 0; i < 2; ++i)
#pragma unroll
        for (int j = 0; j < 4; ++j)
          acc[i][j] = __builtin_amdgcn_mfma_f32_16x16x32_bf16(av[i], bv[j],
                                                              acc[i][j], 0, 0, 0);
    }
  }

  // epilogue: z = v + u + bias; rowwise ||z||; out = z/max(||z||,eps)  (fp32)
  float bo[4];
#pragma unroll
  for (int j = 0; j < 4; ++j) bo[j] = bias[64 * wc + 16 * j + (lane & 15)];

  const bf16* urow = unat + ((size_t)b * N_ + n0) * F_;

  float s[2][4];
#pragma unroll
  for (int i = 0; i < 2; ++i)
#pragma unroll
    for (int r = 0; r < 4; ++r) s[i][r] = 0.0f;
#pragma unroll
  for (int i = 0; i < 2; ++i)
#pragma unroll
    for (int j = 0; j < 4; ++j) {
      floatx4 t = acc[i][j];
      const int col = 64 * wc + 16 * j + (lane & 15);
#pragma unroll
      for (int r = 0; r < 4; ++r) {
        const int rowloc = 32 * wr + 16 * i + ((lane >> 4) << 2) + r;
        t[r] += bo[j] + (float)urow[(size_t)rowloc * F_ + col];
        s[i][r] += t[r] * t[r];
      }
      acc[i][j] = t;
    }
  // sum across the 16 column-lanes (C layout: col = lane&15)
#pragma unroll
  for (int m = 1; m < 16; m <<= 1)
#pragma unroll
    for (int i = 0; i < 2; ++i)
#pragma unroll
      for (int r = 0; r < 4; ++r) s[i][r] += __shfl_xor(s[i][r], m, 16);

  if ((lane & 15) == 0) {
#pragma unroll
    for (int i = 0; i < 2; ++i)
#pragma unroll
      for (int r = 0; r < 4; ++r)
        ss[wc][32 * wr + 16 * i + ((lane >> 4) << 2) + r] = s[i][r];
  }
  __syncthreads();

  const size_t outbase = ((size_t)b * N_ + n0) * F_;
#pragma unroll
  for (int i = 0; i < 2; ++i)
#pragma unroll
    for (int r = 0; r < 4; ++r) {
      int rowloc = 32 * wr + 16 * i + ((lane >> 4) << 2) + r;
      float tot = ss[0][rowloc] + ss[1][rowloc];
      float inv = 1.0f / fmaxf(sqrtf(tot), 1e-12f);
      size_t ro = outbase + (size_t)rowloc * F_ + 64 * wc + (lane & 15);
#pragma unroll
      for (int j = 0; j < 4; ++j)
        out[ro + 16 * j] = acc[i][j][r] * inv;
    }
}

extern "C" void kernel_launch(void* const* d_in, const int* in_sizes, int n_in,
                              void* d_out, int out_size, void* d_ws, size_t ws_size,
                              hipStream_t stream) {
  (void)in_sizes; (void)n_in; (void)out_size; (void)ws_size;
  const float* x    = (const float*)d_in[0];  // [8][8192][128] fp32
  const float* adj  = (const float*)d_in[1];  // [8192][8192]   fp32
  const float* w    = (const float*)d_in[2];  // [128][128]     fp32
  const float* bias = (const float*)d_in[3];  // [128]          fp32
  float* out = (float*)d_out;                 // [8][8192][128] fp32
  bf16* u  = (bf16*)d_ws;                     // u[8][8192][128]  bf16, 16 MB
  bf16* ut = u + (size_t)B_ * N_ * F_;        // ut[8][128][8192] bf16, 16 MB

  k0a_xw<<<dim3(4096), dim3(256), 0, stream>>>(x, w, u);
  k0b_transpose<<<dim3(128, 2, 8), dim3(256), 0, stream>>>(u, ut);
  k1_graphconv<<<dim3(64, 8), dim3(512), 0, stream>>>(adj, ut, u, bias, out);
}

// Round 2
// 543.289 us; speedup vs baseline: 1.4350x; 1.2320x over previous
//
#include <hip/hip_runtime.h>
#include <hip/hip_bf16.h>
#include <stdint.h>

// GraphConv: out = normalize((adj@x + x)@W + bias, dim=f)
// R5: k0 stage collapsed into ONE MFMA kernel producing only ut (u^T).
//   K0 : ut[b][o][m] = (x@W)^T   (MFMA bf16, 128x128 tile per block,
//        W transposed in-block from L2-hot 64KB, direct bf16x4 stores)
//   K1 : v = adj@u  (A: fp32->bf16 via regs + swizzled ds_write;
//                    B: global_load_lds with pre-swizzled global source)
//        epilogue: z = v + u + bias (fp32), out = z / max(||z||,eps), fp32.
//        Self-add term now read from ut (scalar gather, same class as before).
// u natural-layout is never materialized (saves 16MB write + a transpose pass).

typedef __bf16 bf16;
typedef __bf16 bf16x4 __attribute__((ext_vector_type(4)));
typedef __bf16 bf16x8 __attribute__((ext_vector_type(8)));
typedef float floatx4 __attribute__((ext_vector_type(4)));

#define B_ 8
#define N_ 8192
#define F_ 128

__device__ __forceinline__ void async_copy16(const void* g, void* l) {
  __builtin_amdgcn_global_load_lds(
      (const __attribute__((address_space(1))) uint32_t*)g,
      (__attribute__((address_space(3))) uint32_t*)l, 16, 0, 0);
}

// ---------------- K0: ut[b][o][m] = (x[b]@W)^T  (fp32 in, bf16 out) --------
// Block: 256 threads (4 waves, 2x2), tile 128 m-rows x 128 o-cols, K=128.
// Fragment geometry identical to k1 (As[row][k], Wt[o][k], XOR chunk swizzle).
__global__ __launch_bounds__(256, 2) void k0_xw_t(const float* __restrict__ x,
                                                  const float* __restrict__ w,
                                                  bf16* __restrict__ ut) {
  __shared__ bf16 As[128][128];   // x tile, chunk-swizzled (chunk ^= row&15)
  __shared__ bf16 Wt[128][128];   // W^T, chunk-swizzled
  const int tid = threadIdx.x;
  const int lane = tid & 63;
  const int l15 = lane & 15;
  const int h = lane >> 4;            // 0..3
  const int wv = tid >> 6;            // 0..3
  const int wr = wv >> 1;             // 0..1: 64-row band
  const int wc = wv & 1;              // 0..1: 64-col half
  const int bm0 = blockIdx.x << 7;    // global row in flattened [B*N]
  const int b = bm0 >> 13;            // 8192 rows per batch
  const int m0 = bm0 & (N_ - 1);

  // ---- stage Wt[o][f] = w[f][o], bf16, swizzled (one-time, w is L2-hot) ----
#pragma unroll
  for (int c = 0; c < 64; ++c) {
    int lin = (c << 8) + tid;         // 0..16383
    int f = lin >> 7, o = lin & 127;  // consecutive tid -> consecutive o
    bf16 v = (bf16)w[(size_t)f * F_ + o];
    int phys = (f >> 3) ^ (o & 15);
    ((bf16*)Wt)[o * 128 + (phys << 3) + (f & 7)] = v;
  }

  // ---- stage As[m][k] = x[bm0+m][k], bf16, swizzled ----
  {
    const int r = tid >> 1;                 // 0..127
    const int colh = (tid & 1) << 6;        // 0 or 64
    const float* xr = x + (size_t)(bm0 + r) * F_ + colh;
#pragma unroll
    for (int q = 0; q < 8; ++q) {
      float4 f0 = *(const float4*)(xr + 8 * q);
      float4 f1 = *(const float4*)(xr + 8 * q + 4);
      bf16x8 pk;
      pk[0] = (bf16)f0.x; pk[1] = (bf16)f0.y; pk[2] = (bf16)f0.z; pk[3] = (bf16)f0.w;
      pk[4] = (bf16)f1.x; pk[5] = (bf16)f1.y; pk[6] = (bf16)f1.z; pk[7] = (bf16)f1.w;
      int c = ((tid & 1) << 3) + q;         // logical chunk 0..15
      int phys = c ^ (r & 15);
      *(bf16x8*)&((bf16*)As)[r * 128 + (phys << 3)] = pk;
    }
  }
  __syncthreads();

  // ---- fragment pointers (swizzle: chunk ^= row&15 == l15) ----
  const bf16* pa[4][4];
  const bf16* pb[4][4];
#pragma unroll
  for (int i = 0; i < 4; ++i)
#pragma unroll
    for (int kk = 0; kk < 4; ++kk)
      pa[i][kk] = &As[64 * wr + 16 * i + l15][(((kk << 2) + h) ^ l15) << 3];
#pragma unroll
  for (int j = 0; j < 4; ++j)
#pragma unroll
    for (int kk = 0; kk < 4; ++kk)
      pb[j][kk] = &Wt[64 * wc + 16 * j + l15][(((kk << 2) + h) ^ l15) << 3];

  floatx4 acc[4][4] = {};
#pragma unroll
  for (int kk = 0; kk < 4; ++kk) {
    bf16x8 av[4], bv[4];
#pragma unroll
    for (int i = 0; i < 4; ++i) av[i] = *(const bf16x8*)pa[i][kk];
#pragma unroll
    for (int j = 0; j < 4; ++j) bv[j] = *(const bf16x8*)pb[j][kk];
#pragma unroll
    for (int i = 0; i < 4; ++i)
#pragma unroll
      for (int j = 0; j < 4; ++j)
        acc[i][j] = __builtin_amdgcn_mfma_f32_16x16x32_bf16(av[i], bv[j],
                                                            acc[i][j], 0, 0, 0);
  }

  // ---- write ut[o][m0 + row] directly (bf16x4 along 4 consecutive m) ----
  bf16* utb = ut + (size_t)b * F_ * N_;
#pragma unroll
  for (int i = 0; i < 4; ++i)
#pragma unroll
    for (int j = 0; j < 4; ++j) {
      const int o = 64 * wc + 16 * j + l15;
      const int mrow = m0 + 64 * wr + 16 * i + (h << 2);
      bf16x4 pk;
#pragma unroll
      for (int r = 0; r < 4; ++r) pk[r] = (bf16)acc[i][j][r];
      *(bf16x4*)(utb + (size_t)o * N_ + mrow) = pk;
    }
}

// ---- K1: v = adj@u; z = v + u + bias; out = z / max(||z||, eps) ----
__global__ __launch_bounds__(512, 4) void k1_graphconv(const float* __restrict__ adj,
                                                       const bf16* __restrict__ ut,
                                                       const float* __restrict__ bias,
                                                       float* __restrict__ out) {
  __shared__ bf16 As[128][64];   // adj tile, bf16, chunk-swizzled
  __shared__ bf16 Bs[128][64];   // ut tile (B^T rows), chunk-swizzled
  __shared__ float ss[2][128];
  const int tid = threadIdx.x;            // 0..511
  const int lane = tid & 63;
  const int wv = tid >> 6;                // 0..7
  const int wr = wv >> 1;                 // 0..3: 32-row band
  const int wc = wv & 1;                  // 0..1: 64-col half
  const int n0 = blockIdx.x << 7;         // 64 n-tiles; XCD = n-tile % 8
  const int b = blockIdx.y;               // 8 b-blocks share adj tile in-XCD
  const bf16* ub = ut + (size_t)b * F_ * N_;

  // ---- B staging: global_load_lds, linear LDS dest, swizzled global src ----
  const int brow = tid >> 3;                    // 0..63 (call 0), +64 (call 1)
  const int blc = (tid & 7) ^ (brow & 7);
  const bf16* gb0 = ub + (size_t)brow * N_ + (blc << 3);
  const bf16* gb1 = ub + (size_t)(brow + 64) * N_ + (blc << 3);
  bf16* lb0 = (bf16*)Bs + tid * 8;
  bf16* lb1 = (bf16*)Bs + (tid + 512) * 8;

  // ---- A staging: fp32 -> bf16 via regs, swizzled ds_write ----
  const int ar = tid >> 2;                      // 0..127
  const int kc = (tid & 3) << 4;                // float offset in row
  const float* gAb = adj + (size_t)(n0 + ar) * N_ + kc;
  const int pc0 = ((tid & 3) << 1) ^ (ar & 7);
  bf16* lA0 = (bf16*)As + ar * 64 + (pc0 << 3);
  bf16* lA1 = (bf16*)As + ar * 64 + ((pc0 ^ 1) << 3);

  // ---- fragment read pointers (swizzle: chunk ^= row&7 == lane&7) ----
  const bf16* pa[2][2];
  const bf16* pb[4][2];
#pragma unroll
  for (int i = 0; i < 2; ++i)
#pragma unroll
    for (int kk = 0; kk < 2; ++kk)
      pa[i][kk] = &As[32 * wr + 16 * i + (lane & 15)]
                     [(((kk << 2) + (lane >> 4)) ^ (lane & 7)) << 3];
#pragma unroll
  for (int j = 0; j < 4; ++j)
#pragma unroll
    for (int kk = 0; kk < 2; ++kk)
      pb[j][kk] = &Bs[64 * wc + 16 * j + (lane & 15)]
                     [(((kk << 2) + (lane >> 4)) ^ (lane & 7)) << 3];

  floatx4 acc[2][4] = {};

  // prefetch A(ks=0)
  float4 pf[4];
#pragma unroll
  for (int q = 0; q < 4; ++q) pf[q] = *(const float4*)(gAb + 4 * q);

  for (int ks = 0; ks < 128; ++ks) {
    __syncthreads();  // compute(ks-1) readers done; pf(ks) arrived
    // B(ks) async copies — only these sit on the pre-compute drain (L2-resident)
    async_copy16(gb0, lb0);
    async_copy16(gb1, lb1);
    gb0 += 64; gb1 += 64;
    // commit A(ks) regs -> bf16 LDS (swizzled)
    bf16x8 lo, hi;
#pragma unroll
    for (int q = 0; q < 2; ++q) {
      float4 f = pf[q];
      lo[4 * q + 0] = (bf16)f.x; lo[4 * q + 1] = (bf16)f.y;
      lo[4 * q + 2] = (bf16)f.z; lo[4 * q + 3] = (bf16)f.w;
    }
#pragma unroll
    for (int q = 0; q < 2; ++q) {
      float4 f = pf[q + 2];
      hi[4 * q + 0] = (bf16)f.x; hi[4 * q + 1] = (bf16)f.y;
      hi[4 * q + 2] = (bf16)f.z; hi[4 * q + 3] = (bf16)f.w;
    }
    *(bf16x8*)lA0 = lo;
    *(bf16x8*)lA1 = hi;
    __syncthreads();  // drains B copies + A ds_writes
    // prefetch A(ks+1) AFTER the barrier: latency hides under the MFMA phase
    const float* gn = gAb + ((size_t)((ks + 1) & 127) << 6);
#pragma unroll
    for (int q = 0; q < 4; ++q) pf[q] = *(const float4*)(gn + 4 * q);

#pragma unroll
    for (int kk = 0; kk < 2; ++kk) {
      bf16x8 av[2], bv[4];
#pragma unroll
      for (int i = 0; i < 2; ++i) av[i] = *(const bf16x8*)pa[i][kk];
#pragma unroll
      for (int j = 0; j < 4; ++j) bv[j] = *(const bf16x8*)pb[j][kk];
#pragma unroll
      for (int i = 0; i < 2; ++i)
#pragma unroll
        for (int j = 0; j < 4; ++j)
          acc[i][j] = __builtin_amdgcn_mfma_f32_16x16x32_bf16(av[i], bv[j],
                                                              acc[i][j], 0, 0, 0);
    }
  }

  // epilogue: z = v + u + bias; rowwise ||z||; out = z/max(||z||,eps)  (fp32)
  float bo[4];
#pragma unroll
  for (int j = 0; j < 4; ++j) bo[j] = bias[64 * wc + 16 * j + (lane & 15)];

  float s[2][4];
#pragma unroll
  for (int i = 0; i < 2; ++i)
#pragma unroll
    for (int r = 0; r < 4; ++r) s[i][r] = 0.0f;
#pragma unroll
  for (int i = 0; i < 2; ++i)
#pragma unroll
    for (int j = 0; j < 4; ++j) {
      floatx4 t = acc[i][j];
      const int col = 64 * wc + 16 * j + (lane & 15);
#pragma unroll
      for (int r = 0; r < 4; ++r) {
        const int rowloc = 32 * wr + 16 * i + ((lane >> 4) << 2) + r;
        // self-add from ut (u never materialized in natural layout)
        t[r] += bo[j] + (float)ub[(size_t)col * N_ + n0 + rowloc];
        s[i][r] += t[r] * t[r];
      }
      acc[i][j] = t;
    }
  // sum across the 16 column-lanes (C layout: col = lane&15)
#pragma unroll
  for (int m = 1; m < 16; m <<= 1)
#pragma unroll
    for (int i = 0; i < 2; ++i)
#pragma unroll
      for (int r = 0; r < 4; ++r) s[i][r] += __shfl_xor(s[i][r], m, 16);

  if ((lane & 15) == 0) {
#pragma unroll
    for (int i = 0; i < 2; ++i)
#pragma unroll
      for (int r = 0; r < 4; ++r)
        ss[wc][32 * wr + 16 * i + ((lane >> 4) << 2) + r] = s[i][r];
  }
  __syncthreads();

  const size_t outbase = ((size_t)b * N_ + n0) * F_;
#pragma unroll
  for (int i = 0; i < 2; ++i)
#pragma unroll
    for (int r = 0; r < 4; ++r) {
      int rowloc = 32 * wr + 16 * i + ((lane >> 4) << 2) + r;
      float tot = ss[0][rowloc] + ss[1][rowloc];
      float inv = 1.0f / fmaxf(sqrtf(tot), 1e-12f);
      size_t ro = outbase + (size_t)rowloc * F_ + 64 * wc + (lane & 15);
#pragma unroll
      for (int j = 0; j < 4; ++j)
        out[ro + 16 * j] = acc[i][j][r] * inv;
    }
}

extern "C" void kernel_launch(void* const* d_in, const int* in_sizes, int n_in,
                              void* d_out, int out_size, void* d_ws, size_t ws_size,
                              hipStream_t stream) {
  (void)in_sizes; (void)n_in; (void)out_size; (void)ws_size;
  const float* x    = (const float*)d_in[0];  // [8][8192][128] fp32
  const float* adj  = (const float*)d_in[1];  // [8192][8192]   fp32
  const float* w    = (const float*)d_in[2];  // [128][128]     fp32
  const float* bias = (const float*)d_in[3];  // [128]          fp32
  float* out = (float*)d_out;                 // [8][8192][128] fp32
  bf16* ut = (bf16*)d_ws;                     // ut[8][128][8192] bf16, 16 MB

  k0_xw_t<<<dim3(512), dim3(256), 0, stream>>>(x, w, ut);
  k1_graphconv<<<dim3(64, 8), dim3(512), 0, stream>>>(adj, ut, bias, out);
}